// Round 1
// baseline (1089.351 us; speedup 1.0000x reference)
//
#include <hip/hip_runtime.h>
#include <math.h>

#define BATCH  32768
#define D      128
#define K      6400
#define KC     64
#define TILE_R 64
#define TILE_C 64
#define NCHUNK (K / TILE_C)   // 100

// ---- c2[k] = ||centers[k]||^2 ----
__global__ __launch_bounds__(64) void c2_kernel(const float* __restrict__ centers,
                                                float* __restrict__ c2) {
    int k = blockIdx.x * 64 + threadIdx.x;
    const float4* c4 = (const float4*)centers + (size_t)k * (D / 4);
    float s = 0.f;
#pragma unroll
    for (int i = 0; i < D / 4; ++i) {
        float4 v = c4[i];
        s = fmaf(v.x, v.x, s); s = fmaf(v.y, v.y, s);
        s = fmaf(v.z, v.z, s); s = fmaf(v.w, v.w, s);
    }
    c2[k] = s;
}

// ---- fused distance + argmin + outputs ----
// Block: 256 threads = 16 (tc, center dir) x 16 (tr, row dir).
// Tile: 64 rows x 64 centers/chunk, 4x4 micro-tile per thread.
// LDS: two 32 KB float4 arrays, XOR-swizzled (no pad): (r,d4) -> r*32 + (d4 ^ (r&31)).
//   x-reads: 16-lane broadcast + 4 distinct bank-quads -> conflict-free.
//   c-reads: 2-way (free). Staging writes: contiguous within row -> full BW.
__global__ __launch_bounds__(256, 2) void dist_kernel(
    const float* __restrict__ x, const float* __restrict__ centers,
    const float* __restrict__ c2g, float* __restrict__ out) {
    __shared__ float4 xs4[TILE_R * 32];
    __shared__ float4 cs4[TILE_C * 32];

    const int t   = threadIdx.x;
    const int tc  = t & 15;
    const int tr  = t >> 4;
    const int gr0 = blockIdx.x * TILE_R;

    // stage x tile (coalesced global float4 reads)
    {
        const float4* xg4 = (const float4*)x + (size_t)gr0 * 32;
#pragma unroll
        for (int i = 0; i < 8; ++i) {
            int lin = t + i * 256;
            int r = lin >> 5, d4 = lin & 31;
            xs4[r * 32 + (d4 ^ (r & 31))] = xg4[lin];
        }
    }
    __syncthreads();

    // per-thread row norms for rows tr + 16*i (kept in registers)
    float x2r[4];
#pragma unroll
    for (int i = 0; i < 4; ++i) {
        int r = tr + 16 * i, sw = r & 31;
        float s = 0.f;
#pragma unroll
        for (int d4 = 0; d4 < 32; ++d4) {
            float4 v = xs4[r * 32 + (d4 ^ sw)];
            s = fmaf(v.x, v.x, s); s = fmaf(v.y, v.y, s);
            s = fmaf(v.z, v.z, s); s = fmaf(v.w, v.w, s);
        }
        x2r[i] = s;
    }

    float bv[4]; int bi[4];
#pragma unroll
    for (int i = 0; i < 4; ++i) { bv[i] = 3.4e38f; bi[i] = 0x7fffffff; }

    for (int ch = 0; ch < NCHUNK; ++ch) {
        const int c0 = ch * TILE_C;
        __syncthreads();  // previous chunk's cs4 reads complete
        const float4* cg4 = (const float4*)centers + (size_t)c0 * 32;
#pragma unroll
        for (int i = 0; i < 8; ++i) {
            int lin = t + i * 256;
            int kl = lin >> 5, d4 = lin & 31;
            cs4[kl * 32 + (d4 ^ (kl & 31))] = cg4[lin];
        }
        float c2v[4];
#pragma unroll
        for (int j = 0; j < 4; ++j) c2v[j] = c2g[c0 + tc + 16 * j];
        __syncthreads();

        float acc[4][4];
#pragma unroll
        for (int i = 0; i < 4; ++i)
#pragma unroll
            for (int j = 0; j < 4; ++j) acc[i][j] = 0.f;

#pragma unroll 2
        for (int d4 = 0; d4 < 32; ++d4) {
            float4 xv[4], cv[4];
#pragma unroll
            for (int i = 0; i < 4; ++i) {
                int r = tr + 16 * i;
                xv[i] = xs4[r * 32 + (d4 ^ (r & 31))];
            }
#pragma unroll
            for (int j = 0; j < 4; ++j) {
                int c = tc + 16 * j;
                cv[j] = cs4[c * 32 + (d4 ^ (c & 31))];
            }
#pragma unroll
            for (int i = 0; i < 4; ++i)
#pragma unroll
                for (int j = 0; j < 4; ++j) {
                    acc[i][j] = fmaf(xv[i].x, cv[j].x, acc[i][j]);
                    acc[i][j] = fmaf(xv[i].y, cv[j].y, acc[i][j]);
                    acc[i][j] = fmaf(xv[i].z, cv[j].z, acc[i][j]);
                    acc[i][j] = fmaf(xv[i].w, cv[j].w, acc[i][j]);
                }
        }

        // score = c2 - 2*dot (x2 is row-constant; added only for min_distances)
#pragma unroll
        for (int j = 0; j < 4; ++j) {
            int cidx = c0 + tc + 16 * j;
#pragma unroll
            for (int i = 0; i < 4; ++i) {
                float s = fmaf(-2.f, acc[i][j], c2v[j]);
                // indices visited in ascending order per lane-slot: strict < keeps
                // first occurrence; explicit tie-break for the cross-lane stage
                if (s < bv[i]) { bv[i] = s; bi[i] = cidx; }
            }
        }
    }

    float* out_q   = out;
    float* out_clu = out + (size_t)BATCH * D;
    float* out_md  = out_clu + BATCH;
    float* out_cls = out_md + BATCH;

    // argmin reduction across the 16 tc lanes (same tr = consecutive lanes)
    int ixr[4];
#pragma unroll
    for (int i = 0; i < 4; ++i) {
        float v = bv[i]; int ix = bi[i];
#pragma unroll
        for (int m = 8; m >= 1; m >>= 1) {
            float ov = __shfl_xor(v, m, 64);
            int   oi = __shfl_xor(ix, m, 64);
            if (ov < v || (ov == v && oi < ix)) { v = ov; ix = oi; }
        }
        ixr[i] = ix;
        if (tc == 0) {
            int r = tr + 16 * i;
            float sq = x2r[i] + v;
            out_md[gr0 + r]  = sqrtf(fmaxf(sq, 0.f));
            out_clu[gr0 + r] = (float)(ix & (KC - 1));
            out_cls[gr0 + r] = (float)(ix >> 6);
        }
    }

    __syncthreads();              // all waves done reading cs4
    int* bis = (int*)cs4;         // alias dead center tile for index exchange
    if (tc == 0) {
#pragma unroll
        for (int i = 0; i < 4; ++i) bis[tr + 16 * i] = ixr[i];
    }
    __syncthreads();

    // gather quantized = x + (c - x)  (matches reference STE arithmetic)
    const float4* cg4 = (const float4*)centers;
    float4* oq4 = (float4*)out_q;
    int rp = t >> 5, dt = t & 31;
#pragma unroll
    for (int p = 0; p < 8; ++p) {
        int r = p * 8 + rp;
        int ix = bis[r];
        float4 c  = cg4[(size_t)ix * 32 + dt];
        float4 xv = xs4[r * 32 + (dt ^ (r & 31))];
        float4 o;
        o.x = xv.x + (c.x - xv.x);
        o.y = xv.y + (c.y - xv.y);
        o.z = xv.z + (c.z - xv.z);
        o.w = xv.w + (c.w - xv.w);
        oq4[(size_t)(gr0 + r) * 32 + dt] = o;
    }
}

extern "C" void kernel_launch(void* const* d_in, const int* in_sizes, int n_in,
                              void* d_out, int out_size, void* d_ws, size_t ws_size,
                              hipStream_t stream) {
    const float* x       = (const float*)d_in[0];
    const float* centers = (const float*)d_in[1];
    // d_in[2] = labels (int64) — unused by the forward computation
    float* out = (float*)d_out;
    float* c2  = (float*)d_ws;  // 6400 floats, rewritten every call

    c2_kernel<<<K / 64, 64, 0, stream>>>(centers, c2);
    dist_kernel<<<BATCH / TILE_R, 256, 0, stream>>>(x, centers, c2, out);
}

// Round 2
// 244.153 us; speedup vs baseline: 4.4618x; 4.4618x over previous
//
#include <hip/hip_runtime.h>
#include <math.h>

#define BATCH  32768
#define D      128
#define K      6400
#define KC     64
#define ROWS_PER_BLOCK 64
#define CHUNK_C 128
#define NCHUNK (K / CHUNK_C)   // 50

typedef _Float16 half8 __attribute__((ext_vector_type(8)));
typedef float    floatx4 __attribute__((ext_vector_type(4)));

typedef __attribute__((address_space(3))) unsigned       lds_uint;
typedef __attribute__((address_space(1))) const unsigned glb_uint;

__device__ __forceinline__ void async_lds16(const void* g, void* l) {
    __builtin_amdgcn_global_load_lds((glb_uint*)g, (lds_uint*)l, 16, 0, 0);
}

// ---- c2[k] = ||centers[k]||^2 (fp32) ----
__global__ __launch_bounds__(64) void c2_kernel(const float* __restrict__ centers,
                                                float* __restrict__ c2) {
    int k = blockIdx.x * 64 + threadIdx.x;
    const float4* c4 = (const float4*)centers + (size_t)k * (D / 4);
    float s = 0.f;
#pragma unroll
    for (int i = 0; i < D / 4; ++i) {
        float4 v = c4[i];
        s = fmaf(v.x, v.x, s); s = fmaf(v.y, v.y, s);
        s = fmaf(v.z, v.z, s); s = fmaf(v.w, v.w, s);
    }
    c2[k] = s;
}

// ---- pack centers into split-fp16 hi/lo, chunk-ordered for global_load_lds ----
// ws linear 16B-chunk index n = ch*2048 + u*128 + cw  holds
// center (ch*128+cw), k in [u*8, u*8+8).
__global__ __launch_bounds__(256) void pack_kernel(const float* __restrict__ centers,
                                                   _Float16* __restrict__ wh,
                                                   _Float16* __restrict__ wl) {
    int tid = blockIdx.x * 256 + threadIdx.x;   // 0 .. K*16-1
    int ch = tid >> 11;
    int rr = tid & 2047;
    int u  = rr >> 7;
    int cw = rr & 127;
    int center = ch * CHUNK_C + cw;
    const float* src = centers + (size_t)center * D + u * 8;
    float4 a = *(const float4*)src;
    float4 b = *(const float4*)(src + 4);
    float f[8] = {a.x, a.y, a.z, a.w, b.x, b.y, b.z, b.w};
    half8 h, l;
#pragma unroll
    for (int j = 0; j < 8; ++j) {
        _Float16 hi = (_Float16)f[j];
        h[j] = hi;
        l[j] = (_Float16)(f[j] - (float)hi);
    }
    *(half8*)(wh + (size_t)tid * 8) = h;
    *(half8*)(wl + (size_t)tid * 8) = l;
}

// ---- main fused kernel ----
// Block: 256 threads = 4 waves. Block owns 64 rows.
// wave w: rowhalf = w&1 (rows rowhalf*32 .. +31), chalf = w>>1 (centers chalf*64 .. +63 of chunk).
// Wave tile: 32 rows x 64 centers, A (x rows, split-fp16) register-resident all kernel.
// 3-pass split MFMA: acc += Ah*Bh + Ah*Bl + Al*Bh  (error ~3e-6 on score).
// Track best-2 per (row, center-half); exact fp32 refine of <=4 candidates/row at end.
__global__ __launch_bounds__(256, 2) void dist_kernel(
    const float* __restrict__ x, const float* __restrict__ centers,
    const _Float16* __restrict__ wh, const _Float16* __restrict__ wl,
    const float* __restrict__ c2g, float* __restrict__ out) {
    __shared__ half8 cs_hi[2048];   // [u:16][cw:128] 16B chunks, 32 KB
    __shared__ half8 cs_lo[2048];   // 32 KB

    const int t    = threadIdx.x;
    const int w    = t >> 6;
    const int L    = t & 63;
    const int quad = L >> 4;
    const int n16  = L & 15;
    const int rowhalf = w & 1;
    const int chalf   = w >> 1;
    const int cwbase  = chalf * 64;
    const int gr0  = blockIdx.x * ROWS_PER_BLOCK;

    // ---- preload A fragments (this wave's 32 rows, all 128 k, hi+lo) ----
    half8 Ah[2][4], Al[2][4];
#pragma unroll
    for (int rt = 0; rt < 2; ++rt) {
        int r = gr0 + rowhalf * 32 + rt * 16 + n16;
        const float* xr = x + (size_t)r * D + quad * 8;
#pragma unroll
        for (int ks = 0; ks < 4; ++ks) {
            float4 a = *(const float4*)(xr + ks * 32);
            float4 b = *(const float4*)(xr + ks * 32 + 4);
            float f[8] = {a.x, a.y, a.z, a.w, b.x, b.y, b.z, b.w};
            half8 h, l;
#pragma unroll
            for (int j = 0; j < 8; ++j) {
                _Float16 hi = (_Float16)f[j];
                h[j] = hi;
                l[j] = (_Float16)(f[j] - (float)hi);
            }
            Ah[rt][ks] = h;
            Al[rt][ks] = l;
        }
    }

    float b1[8], b2[8];
    int   j1_[8], j2_[8];
#pragma unroll
    for (int k = 0; k < 8; ++k) { b1[k] = 3.4e38f; b2[k] = 3.4e38f; j1_[k] = 0; j2_[k] = 0; }

    for (int ch = 0; ch < NCHUNK; ++ch) {
        const int c0 = ch * CHUNK_C;
        __syncthreads();   // previous chunk's cs reads complete
        const char* gh = (const char*)wh + (size_t)ch * 32768;
        const char* gl = (const char*)wl + (size_t)ch * 32768;
#pragma unroll
        for (int i = 0; i < 8; ++i) {
            int seg = w + i * 4;                       // wave-uniform
            async_lds16(gh + seg * 1024 + L * 16, (char*)cs_hi + seg * 1024);
            async_lds16(gl + seg * 1024 + L * 16, (char*)cs_lo + seg * 1024);
        }
        float c2v[4];
#pragma unroll
        for (int ct = 0; ct < 4; ++ct) c2v[ct] = c2g[c0 + cwbase + ct * 16 + n16];
        __syncthreads();   // staging complete

        floatx4 acc[2][4];
#pragma unroll
        for (int rt = 0; rt < 2; ++rt)
#pragma unroll
            for (int ct = 0; ct < 4; ++ct) acc[rt][ct] = (floatx4){0.f, 0.f, 0.f, 0.f};

#pragma unroll
        for (int ks = 0; ks < 4; ++ks) {
            const half8* ph = cs_hi + (ks * 4 + quad) * 128 + cwbase + n16;
            const half8* pl = cs_lo + (ks * 4 + quad) * 128 + cwbase + n16;
#pragma unroll
            for (int ct = 0; ct < 4; ++ct) {
                half8 Bh = ph[ct * 16];
                half8 Bl = pl[ct * 16];
#pragma unroll
                for (int rt = 0; rt < 2; ++rt) {
                    acc[rt][ct] = __builtin_amdgcn_mfma_f32_16x16x32_f16(Ah[rt][ks], Bh, acc[rt][ct], 0, 0, 0);
                    acc[rt][ct] = __builtin_amdgcn_mfma_f32_16x16x32_f16(Ah[rt][ks], Bl, acc[rt][ct], 0, 0, 0);
                    acc[rt][ct] = __builtin_amdgcn_mfma_f32_16x16x32_f16(Al[rt][ks], Bh, acc[rt][ct], 0, 0, 0);
                }
            }
        }

        // best-2 tracking: score = c2 - 2*dot (x2 row-constant, irrelevant for argmin)
#pragma unroll
        for (int ct = 0; ct < 4; ++ct) {
            int idx = c0 + cwbase + ct * 16 + n16;
#pragma unroll
            for (int rt = 0; rt < 2; ++rt)
#pragma unroll
                for (int reg = 0; reg < 4; ++reg) {
                    float s = fmaf(-2.f, acc[rt][ct][reg], c2v[ct]);
                    int k = rt * 4 + reg;
                    bool bet1 = s < b1[k];
                    bool bet2 = s < b2[k];
                    float nb2 = bet1 ? b1[k] : (bet2 ? s : b2[k]);
                    int   nj2 = bet1 ? j1_[k] : (bet2 ? idx : j2_[k]);
                    b1[k]  = bet1 ? s : b1[k];
                    j1_[k] = bet1 ? idx : j1_[k];
                    b2[k]  = nb2;
                    j2_[k] = nj2;
                }
        }
    }

    __syncthreads();              // cs arrays free for reuse
    int* candL = (int*)cs_hi;     // [64 rows][4 candidates]

    // cross-lane merge of sorted best-2 pairs across the 16 center-cols
#pragma unroll
    for (int k = 0; k < 8; ++k) {
        float v1 = b1[k], v2 = b2[k];
        int   p1 = j1_[k], p2 = j2_[k];
#pragma unroll
        for (int m = 1; m < 16; m <<= 1) {
            float o1 = __shfl_xor(v1, m, 64), o2 = __shfl_xor(v2, m, 64);
            int   q1 = __shfl_xor(p1, m, 64), q2 = __shfl_xor(p2, m, 64);
            bool firstMine = (v1 < o1) || (v1 == o1 && p1 < q1);
            float nv1 = firstMine ? v1 : o1;  int np1 = firstMine ? p1 : q1;
            float cb  = firstMine ? o1 : v1;  int cpi = firstMine ? q1 : p1;  // loser of firsts
            float ob  = firstMine ? v2 : o2;  int obi = firstMine ? p2 : q2;  // winner's own 2nd
            bool secOwn = (ob < cb) || (ob == cb && obi < cpi);
            v1 = nv1; p1 = np1;
            v2 = secOwn ? ob : cb;  p2 = secOwn ? obi : cpi;
        }
        if (n16 == 0) {
            int rloc = rowhalf * 32 + (k >> 2) * 16 + quad * 4 + (k & 3);
            candL[rloc * 4 + chalf * 2 + 0] = p1;
            candL[rloc * 4 + chalf * 2 + 1] = p2;
        }
    }
    __syncthreads();

    float* out_q   = out;
    float* out_clu = out + (size_t)BATCH * D;
    float* out_md  = out_clu + BATCH;
    float* out_cls = out_md + BATCH;

    // exact fp32 refine: 4 candidates per row, one thread each
    {
        int r = t >> 2, cpos = t & 3;
        int ix = candL[r * 4 + cpos];
        const float4* xr4 = (const float4*)(x + (size_t)(gr0 + r) * D);
        const float4* cr4 = (const float4*)(centers + (size_t)ix * D);
        float dot = 0.f, x2s = 0.f, c2s = 0.f;
#pragma unroll
        for (int d4 = 0; d4 < 32; ++d4) {
            float4 xv = xr4[d4], cv = cr4[d4];
            dot = fmaf(xv.x, cv.x, dot); dot = fmaf(xv.y, cv.y, dot);
            dot = fmaf(xv.z, cv.z, dot); dot = fmaf(xv.w, cv.w, dot);
            x2s = fmaf(xv.x, xv.x, x2s); x2s = fmaf(xv.y, xv.y, x2s);
            x2s = fmaf(xv.z, xv.z, x2s); x2s = fmaf(xv.w, xv.w, x2s);
            c2s = fmaf(cv.x, cv.x, c2s); c2s = fmaf(cv.y, cv.y, c2s);
            c2s = fmaf(cv.z, cv.z, c2s); c2s = fmaf(cv.w, cv.w, c2s);
        }
        float sq = x2s + c2s - 2.f * dot;
#pragma unroll
        for (int m = 1; m < 4; m <<= 1) {
            float osq = __shfl_xor(sq, m, 64);
            int   oix = __shfl_xor(ix, m, 64);
            if (osq < sq || (osq == sq && oix < ix)) { sq = osq; ix = oix; }
        }
        int* winL = (int*)cs_lo;
        if (cpos == 0) {
            out_md[gr0 + r]  = sqrtf(fmaxf(sq, 0.f));
            out_clu[gr0 + r] = (float)(ix & (KC - 1));
            out_cls[gr0 + r] = (float)(ix >> 6);
            winL[r] = ix;
        }
    }
    __syncthreads();

    // quantized = x + (c - x), coalesced
    {
        const int* winL = (const int*)cs_lo;
        const float4* cg4 = (const float4*)centers;
        const float4* xg4 = (const float4*)x + (size_t)gr0 * 32;
        float4* oq4 = (float4*)out_q + (size_t)gr0 * 32;
#pragma unroll
        for (int p = 0; p < 8; ++p) {
            int lin = p * 256 + t;
            int r = lin >> 5, d4 = lin & 31;
            int ix = winL[r];
            float4 cv = cg4[(size_t)ix * 32 + d4];
            float4 xv = xg4[lin];
            float4 o;
            o.x = xv.x + (cv.x - xv.x);
            o.y = xv.y + (cv.y - xv.y);
            o.z = xv.z + (cv.z - xv.z);
            o.w = xv.w + (cv.w - xv.w);
            oq4[lin] = o;
        }
    }
}

extern "C" void kernel_launch(void* const* d_in, const int* in_sizes, int n_in,
                              void* d_out, int out_size, void* d_ws, size_t ws_size,
                              hipStream_t stream) {
    const float* x       = (const float*)d_in[0];
    const float* centers = (const float*)d_in[1];
    // d_in[2] = labels (int64) — unused by the forward computation
    float* out = (float*)d_out;

    _Float16* wh = (_Float16*)d_ws;                 // 6400*128 halves, chunk-ordered
    _Float16* wl = wh + (size_t)K * D;
    float*    c2 = (float*)(wl + (size_t)K * D);

    c2_kernel<<<K / 64, 64, 0, stream>>>(centers, c2);
    pack_kernel<<<(K * 16) / 256, 256, 0, stream>>>(centers, wh, wl);
    dist_kernel<<<BATCH / ROWS_PER_BLOCK, 256, 0, stream>>>(x, centers, wh, wl, c2, out);
}